// Round 8
// baseline (185.894 us; speedup 1.0000x reference)
//
#include <hip/hip_runtime.h>
#include <hip/hip_bf16.h>

typedef __bf16 bf16x8 __attribute__((ext_vector_type(8)));
typedef float f32x16 __attribute__((ext_vector_type(16)));
typedef unsigned short u16;
typedef u16 u16x8 __attribute__((ext_vector_type(8)));

#define DENSE_RC 0.0441941738f   // 1/sqrt(512)
#define CONV_RC  0.0147313913f   // 1/sqrt(9*512)

__device__ inline u16 f2bf(float v) {
  union { float f; unsigned u; } x; x.f = v;
  unsigned r = x.u + 0x7fffu + ((x.u >> 16) & 1u);   // RNE
  return (u16)(r >> 16);
}

__device__ inline void gload16(const void* g, void* l) {
  __builtin_amdgcn_global_load_lds(
      (const __attribute__((address_space(1))) unsigned int*)g,
      (__attribute__((address_space(3))) unsigned int*)l, 16, 0, 0);
}

// ---------- 1. style: s[b][i] = DENSE_RC * (y[b] . w_mod[:,i]) + b_mod[i] + 1
__global__ void style_k(const float* __restrict__ y, const float* __restrict__ wm,
                        const float* __restrict__ bm, float* __restrict__ s) {
  const int tid = threadIdx.x, lane = tid & 63, wv = tid >> 6;
  const int idx = blockIdx.x * 64 + lane;
  const int b = idx >> 9, i = idx & 511;
  const float* yb = y + b * 512;
  float acc = 0.f;
  const int j0 = wv * 128;
#pragma unroll 8
  for (int j = j0; j < j0 + 128; ++j) acc += yb[j] * wm[j * 512 + i];
  __shared__ float red[4][64];
  red[wv][lane] = acc;
  __syncthreads();
  if (wv == 0) {
    float a = red[0][lane] + red[1][lane] + red[2][lane] + red[3][lane];
    s[idx] = a * DENSE_RC + bm[i] + 1.0f;
  }
}

// ---------- 2. wsq[i][o] = sum_t w[t][i][o]^2
__global__ void wsq_k(const float* __restrict__ w, float* __restrict__ wsq) {
  const int idx = blockIdx.x * 256 + threadIdx.x;   // i*512+o
  float a = 0.f;
#pragma unroll
  for (int t = 0; t < 9; ++t) { float v = w[(size_t)t * 262144 + idx]; a += v * v; }
  wsq[idx] = a;
}

// ---------- 3. d[b][o] = rsqrt(CONV_RC^2 * sum_i s^2 * wsq + 1e-8)
__global__ void demod_k(const float* __restrict__ s, const float* __restrict__ wsq,
                        float* __restrict__ dmd) {
  const int tid = threadIdx.x, lane = tid & 63, wv = tid >> 6;
  const int idx = blockIdx.x * 64 + lane;
  const int b = idx >> 9, o = idx & 511;
  const float* sb = s + b * 512;
  float a = 0.f;
  const int i0 = wv * 128;
#pragma unroll 4
  for (int i = i0; i < i0 + 128; ++i) { float sv = sb[i]; a += sv * sv * wsq[i * 512 + o]; }
  __shared__ float red[4][64];
  red[wv][lane] = a;
  __syncthreads();
  if (wv == 0) {
    float t = red[0][lane] + red[1][lane] + red[2][lane] + red[3][lane];
    dmd[idx] = rsqrtf(t * (CONV_RC * CONV_RC) + 1e-8f);
  }
}

// ---------- 4. ww[b][t][o][i] = bf16( w[t][i][o] * CONV_RC * s[b][i] * d[b][o] )
__global__ void modw_k(const float* __restrict__ w, const float* __restrict__ s,
                       const float* __restrict__ dmd, u16* __restrict__ wwb) {
  const int blk = blockIdx.x;               // 9*16*8 = 1152
  const int ob = blk & 7, ib = (blk >> 3) & 15, t = blk >> 7;
  __shared__ float lw[32][65];
  const int tid = threadIdx.x;
#pragma unroll
  for (int k = 0; k < 8; ++k) {
    const int e = tid + k * 256;
    const int i = e >> 6, o = e & 63;
    lw[i][o] = w[(size_t)t * 262144 + (size_t)(ib * 32 + i) * 512 + ob * 64 + o];
  }
  __syncthreads();
  const int oo = tid >> 2, q = tid & 3;
  const int ii0 = q * 8;
  for (int b = 0; b < 8; ++b) {
    const float f = CONV_RC * dmd[b * 512 + ob * 64 + oo];
    u16x8 pk;
#pragma unroll
    for (int j = 0; j < 8; ++j)
      pk[j] = f2bf(lw[ii0 + j][oo] * s[b * 512 + ib * 32 + ii0 + j] * f);
    *(u16x8*)(wwb + ((size_t)(b * 9 + t) * 512 + ob * 64 + oo) * 512 + ib * 32 + ii0) = pk;
  }
}

// ---------- 5a. zero only the 1-px border ring of xpad
__global__ void border_k(u16* __restrict__ xpad) {
  const int idx = blockIdx.x * 256 + threadIdx.x;   // 520*256 = 133120 exact
  const int chunk = idx & 63;
  const int p = (idx >> 6) % 260;
  const int b = idx / (260 * 64);
  int row, col;
  if (p < 66)       { row = 0;       col = p; }
  else if (p < 132) { row = 65;      col = p - 66; }
  else if (p < 196) { row = p - 131; col = 0; }
  else              { row = p - 195; col = 65; }
  u16x8 z = {0, 0, 0, 0, 0, 0, 0, 0};
  *(u16x8*)(xpad + ((size_t)(b * 66 + row) * 66 + col) * 512 + chunk * 8) = z;
}

// ---------- 5b. xpad[b][h+1][wcol+1][i] = bf16(x[b][i][h][wcol])   (NCHW -> padded NHWC)
__global__ void fill_k(const float* __restrict__ x, u16* __restrict__ xpad) {
  const int blk = blockIdx.x;               // 8*64*4 = 2048
  const int ib = blk & 3, hh = (blk >> 2) & 63, b = blk >> 8;
  __shared__ float lx[128][65];
  const int tid = threadIdx.x;
#pragma unroll
  for (int k = 0; k < 2; ++k) {
    const int u = tid + k * 256;
    const int i = u >> 2, w0 = (u & 3) * 16;
    const float* src = x + (size_t)((b * 512 + ib * 128 + i) * 64 + hh) * 64 + w0;
    float tmp[16];
    ((float4*)tmp)[0] = ((const float4*)src)[0];
    ((float4*)tmp)[1] = ((const float4*)src)[1];
    ((float4*)tmp)[2] = ((const float4*)src)[2];
    ((float4*)tmp)[3] = ((const float4*)src)[3];
#pragma unroll
    for (int j = 0; j < 16; ++j) lx[i][w0 + j] = tmp[j];
  }
  __syncthreads();
  const int c = tid >> 2, q = tid & 3;
  const size_t base = ((size_t)(b * 66 + hh + 1) * 66 + (c + 1)) * 512 + ib * 128;
#pragma unroll
  for (int k = 0; k < 4; ++k) {
    const int irow = k * 32 + q * 8;
    u16x8 pk;
#pragma unroll
    for (int j = 0; j < 8; ++j) pk[j] = f2bf(lx[irow + j][c]);
    *(u16x8*)(xpad + base + irow) = pk;
  }
}

// ---------- 6. conv, BK=16 + 32x32x16 MFMA + full pingpong dbuf + B-row dedup + setprio
// block: 256 thr = 4 waves, 64 o x [8 rows x 64 px]; wave = 64o x 2 rows (128 px).
// Per buffer: WS [9 t][64 o][16 i] 18432B (chunks 0..1151) + XS [10 r][66 c][16 i]
// 21120B (chunks 1152..2471) = 39552B; dbuf 79104B -> 2 blocks/CU (2 waves/SIMD,
// independent barrier phases). Per kb16 (32 iters): stage(kb+1 -> buf^1) FIRST, then
// compute(buf) [ds_read + MFMA], then one vmcnt(0)+barrier (loads had full compute
// phase to land). B-row dedup: input row ty+hf shared between (ty,1) and (ty+1,0):
// tx-outer/ty-inner chain R0..R3 reads each (row,tx) window once: 48 B-reads/wave-kb32.
// MFMA 32x32x16: A row=l&31, k=(l>>5)*8+j (K-doubling rule from verified 16x16x32);
// C/D: col=lane&31, row=(reg&3)+8*(reg>>2)+4*(lane>>5) [m74/m101-verified].
// 16B-chunk XOR swizzle per region (phys = log ^ ((log>>3)&3)), source-side
// pre-swizzle for linear global_load_lds dest, same XOR on reads.
__global__ __launch_bounds__(256, 2) void conv_k(const u16* __restrict__ xpad,
                                                 const u16* __restrict__ wwb,
                                                 float* __restrict__ out) {
  __shared__ __align__(1024) char SM[79104];
  const int raw = (int)blockIdx.x;          // 512 blocks
  const int pt = raw >> 6, ot = (raw >> 3) & 7, b = raw & 7;  // XCD b gets batch b
  const int tid = threadIdx.x;
  const int lane = tid & 63, wv = tid >> 6; // wave wv: output rows h0+2wv, h0+2wv+1
  const int h0 = pt * 8;

  const size_t xbase = (size_t)(b * 66 + h0) * (66 * 512);

  // ---- staging source pointers (10 rounds; source-side swizzle; +16 u16 per kb16)
  const u16* sp[10];
#pragma unroll
  for (int r = 0; r < 10; ++r) {
    const int cc = tid + r * 256;
    if (cc < 1152) {                        // WS chunk (region-relative = cc)
      const int lc = cc ^ ((cc >> 3) & 3);
      const int t = lc >> 7, o = (lc >> 1) & 63, i8 = lc & 1;
      sp[r] = wwb + ((size_t)(b * 9 + t) * 512 + ot * 64 + o) * 512 + i8 * 8;
    } else {                                // XS chunk
      const int p = cc - 1152;
      const int lc = p ^ ((p >> 3) & 3);
      const int rc = lc >> 1, i8 = lc & 1;
      sp[r] = xpad + xbase + (size_t)rc * 512 + i8 * 8;
    }
  }

  // ---- read-side swizzled offsets
  const int l2 = ((lane & 31) << 1) | (lane >> 5);
  const int AoffT = (l2 ^ ((l2 >> 3) & 3)) * 16;     // + t*2048 + mi*1024
  int Boff[4][3];
#pragma unroll
  for (int rr = 0; rr < 4; ++rr)
#pragma unroll
    for (int tx = 0; tx < 3; ++tx) {
      const int ch = ((2 * wv + rr) * 66 + tx) * 2 + l2;
      Boff[rr][tx] = (ch ^ ((ch >> 3) & 3)) * 16;    // n=1 frag at +1024 (separable)
    }

  f32x16 acc[2][2][2];                               // [mi][hf][n]
#pragma unroll
  for (int mi = 0; mi < 2; ++mi)
#pragma unroll
    for (int hf = 0; hf < 2; ++hf)
#pragma unroll
      for (int n = 0; n < 2; ++n)
#pragma unroll
        for (int e = 0; e < 16; ++e) acc[mi][hf][n][e] = 0.f;

#define LOADB(bf, rr, tx, ofs) { \
    const char* _p = SM + (ofs) + 18432 + Boff[rr][tx]; \
    bf[0] = *(const bf16x8*)_p; bf[1] = *(const bf16x8*)(_p + 1024); }
#define LOADA(af, t, ofs) { \
    const char* _p = SM + (ofs) + AoffT + (t) * 2048; \
    af[0] = *(const bf16x8*)_p; af[1] = *(const bf16x8*)(_p + 1024); }
#define TAP(af, Blo, Bhi) \
    __builtin_amdgcn_s_setprio(1); \
    acc[0][0][0] = __builtin_amdgcn_mfma_f32_32x32x16_bf16(af[0], Blo[0], acc[0][0][0], 0, 0, 0); \
    acc[0][0][1] = __builtin_amdgcn_mfma_f32_32x32x16_bf16(af[0], Blo[1], acc[0][0][1], 0, 0, 0); \
    acc[0][1][0] = __builtin_amdgcn_mfma_f32_32x32x16_bf16(af[0], Bhi[0], acc[0][1][0], 0, 0, 0); \
    acc[0][1][1] = __builtin_amdgcn_mfma_f32_32x32x16_bf16(af[0], Bhi[1], acc[0][1][1], 0, 0, 0); \
    acc[1][0][0] = __builtin_amdgcn_mfma_f32_32x32x16_bf16(af[1], Blo[0], acc[1][0][0], 0, 0, 0); \
    acc[1][0][1] = __builtin_amdgcn_mfma_f32_32x32x16_bf16(af[1], Blo[1], acc[1][0][1], 0, 0, 0); \
    acc[1][1][0] = __builtin_amdgcn_mfma_f32_32x32x16_bf16(af[1], Bhi[0], acc[1][1][0], 0, 0, 0); \
    acc[1][1][1] = __builtin_amdgcn_mfma_f32_32x32x16_bf16(af[1], Bhi[1], acc[1][1][1], 0, 0, 0); \
    __builtin_amdgcn_s_setprio(0);

  auto stage = [&](int ofs) {
#pragma unroll
    for (int r = 0; r < 9; ++r)
      gload16(sp[r], SM + ofs + (tid + r * 256) * 16);
    if (tid < 168) gload16(sp[9], SM + ofs + (tid + 2304) * 16);
#pragma unroll
    for (int r = 0; r < 10; ++r) sp[r] += 16;
  };

  auto compute = [&](int ofs) {
#pragma unroll
    for (int tx = 0; tx < 3; ++tx) {
      bf16x8 R0[2], R1[2], R2[2], R3[2], af0[2], af1[2], af2[2];
      LOADB(R0, 0, tx, ofs);
      LOADB(R1, 1, tx, ofs);
      LOADA(af0, tx, ofs);                 // t = 0*3+tx
      TAP(af0, R0, R1);
      LOADB(R2, 2, tx, ofs);
      LOADA(af1, 3 + tx, ofs);
      TAP(af1, R1, R2);
      LOADB(R3, 3, tx, ofs);
      LOADA(af2, 6 + tx, ofs);
      TAP(af2, R2, R3);
    }
  };

  // prologue
  stage(0);
  asm volatile("s_waitcnt vmcnt(0)" ::: "memory");
  __syncthreads();

  int cofs = 0, nofs = 39552;
  for (int kb = 0; kb < 31; ++kb) {
    stage(nofs);                 // prefetch kb+1 — flies during compute
    compute(cofs);
    asm volatile("s_waitcnt vmcnt(0)" ::: "memory");
    __syncthreads();
    const int tsw = cofs; cofs = nofs; nofs = tsw;
  }
  compute(cofs);                 // kb = 31

  // ---- C write: D col = lane&31 (px), row = (reg&3)+8*(reg>>2)+4*(lane>>5) (o)
  const int pxl = lane & 31, oh = (lane >> 5) * 4;
#pragma unroll
  for (int mi = 0; mi < 2; ++mi)
#pragma unroll
    for (int hf = 0; hf < 2; ++hf) {
      const int h = h0 + 2 * wv + hf;
#pragma unroll
      for (int n = 0; n < 2; ++n) {
        const int wc = n * 32 + pxl;
#pragma unroll
        for (int reg = 0; reg < 16; ++reg) {
          const int o = ot * 64 + mi * 32 + (reg & 3) + 8 * (reg >> 2) + oh;
          out[((size_t)(b * 512 + o) * 64 + h) * 64 + wc] = acc[mi][hf][n][reg];
        }
      }
    }
#undef LOADB
#undef LOADA
#undef TAP
}

extern "C" void kernel_launch(void* const* d_in, const int* in_sizes, int n_in,
                              void* d_out, int out_size, void* d_ws, size_t ws_size,
                              hipStream_t stream) {
  const float* x     = (const float*)d_in[0];   // [8,512,64,64]
  const float* y     = (const float*)d_in[1];   // [8,512]
  const float* w     = (const float*)d_in[2];   // [3,3,512,512]
  const float* w_mod = (const float*)d_in[3];   // [512,512]
  const float* b_mod = (const float*)d_in[4];   // [512]
  float* out = (float*)d_out;

  char* ws = (char*)d_ws;
  float* s    = (float*)(ws);                               // 16 KB
  float* dmd  = (float*)(ws + 16384);                       // 16 KB
  float* wsq  = (float*)(ws + 32768);                       // 1 MB
  u16*   wwb  = (u16*)(ws + 32768 + 1048576);               // 37,748,736 B
  u16*   xpad = (u16*)(ws + 32768 + 1048576 + 37748736);    // 35,684,352 B

  style_k<<<64, 256, 0, stream>>>(y, w_mod, b_mod, s);
  wsq_k<<<1024, 256, 0, stream>>>(w, wsq);
  demod_k<<<64, 256, 0, stream>>>(s, wsq, dmd);
  modw_k<<<1152, 256, 0, stream>>>(w, s, dmd, wwb);
  border_k<<<520, 256, 0, stream>>>(xpad);
  fill_k<<<2048, 256, 0, stream>>>(x, xpad);
  conv_k<<<512, 256, 0, stream>>>(xpad, wwb, out);
}

// Round 10
// 174.034 us; speedup vs baseline: 1.0682x; 1.0682x over previous
//
#include <hip/hip_runtime.h>
#include <hip/hip_bf16.h>

typedef __bf16 bf16x8 __attribute__((ext_vector_type(8)));
typedef float f32x16 __attribute__((ext_vector_type(16)));
typedef unsigned short u16;
typedef u16 u16x8 __attribute__((ext_vector_type(8)));

#define DENSE_RC 0.0441941738f   // 1/sqrt(512)
#define CONV_RC  0.0147313913f   // 1/sqrt(9*512)

__device__ inline u16 f2bf(float v) {
  union { float f; unsigned u; } x; x.f = v;
  unsigned r = x.u + 0x7fffu + ((x.u >> 16) & 1u);   // RNE
  return (u16)(r >> 16);
}

__device__ inline void gload16(const void* g, void* l) {
  __builtin_amdgcn_global_load_lds(
      (const __attribute__((address_space(1))) unsigned int*)g,
      (__attribute__((address_space(3))) unsigned int*)l, 16, 0, 0);
}

// ---------- 1. style: s[b][i] = DENSE_RC * (y[b] . w_mod[:,i]) + b_mod[i] + 1
__global__ void style_k(const float* __restrict__ y, const float* __restrict__ wm,
                        const float* __restrict__ bm, float* __restrict__ s) {
  const int tid = threadIdx.x, lane = tid & 63, wv = tid >> 6;
  const int idx = blockIdx.x * 64 + lane;
  const int b = idx >> 9, i = idx & 511;
  const float* yb = y + b * 512;
  float acc = 0.f;
  const int j0 = wv * 128;
#pragma unroll 8
  for (int j = j0; j < j0 + 128; ++j) acc += yb[j] * wm[j * 512 + i];
  __shared__ float red[4][64];
  red[wv][lane] = acc;
  __syncthreads();
  if (wv == 0) {
    float a = red[0][lane] + red[1][lane] + red[2][lane] + red[3][lane];
    s[idx] = a * DENSE_RC + bm[i] + 1.0f;
  }
}

// ---------- 2. wsq[i][o] = sum_t w[t][i][o]^2
__global__ void wsq_k(const float* __restrict__ w, float* __restrict__ wsq) {
  const int idx = blockIdx.x * 256 + threadIdx.x;   // i*512+o
  float a = 0.f;
#pragma unroll
  for (int t = 0; t < 9; ++t) { float v = w[(size_t)t * 262144 + idx]; a += v * v; }
  wsq[idx] = a;
}

// ---------- 3. d[b][o] = rsqrt(CONV_RC^2 * sum_i s^2 * wsq + 1e-8)
__global__ void demod_k(const float* __restrict__ s, const float* __restrict__ wsq,
                        float* __restrict__ dmd) {
  const int tid = threadIdx.x, lane = tid & 63, wv = tid >> 6;
  const int idx = blockIdx.x * 64 + lane;
  const int b = idx >> 9, o = idx & 511;
  const float* sb = s + b * 512;
  float a = 0.f;
  const int i0 = wv * 128;
#pragma unroll 4
  for (int i = i0; i < i0 + 128; ++i) { float sv = sb[i]; a += sv * sv * wsq[i * 512 + o]; }
  __shared__ float red[4][64];
  red[wv][lane] = a;
  __syncthreads();
  if (wv == 0) {
    float t = red[0][lane] + red[1][lane] + red[2][lane] + red[3][lane];
    dmd[idx] = rsqrtf(t * (CONV_RC * CONV_RC) + 1e-8f);
  }
}

// ---------- 4. ww[b][t][o][i] = bf16( w[t][i][o] * CONV_RC * s[b][i] * d[b][o] )
__global__ void modw_k(const float* __restrict__ w, const float* __restrict__ s,
                       const float* __restrict__ dmd, u16* __restrict__ wwb) {
  const int blk = blockIdx.x;               // 9*16*8 = 1152
  const int ob = blk & 7, ib = (blk >> 3) & 15, t = blk >> 7;
  __shared__ float lw[32][65];
  const int tid = threadIdx.x;
#pragma unroll
  for (int k = 0; k < 8; ++k) {
    const int e = tid + k * 256;
    const int i = e >> 6, o = e & 63;
    lw[i][o] = w[(size_t)t * 262144 + (size_t)(ib * 32 + i) * 512 + ob * 64 + o];
  }
  __syncthreads();
  const int oo = tid >> 2, q = tid & 3;
  const int ii0 = q * 8;
  for (int b = 0; b < 8; ++b) {
    const float f = CONV_RC * dmd[b * 512 + ob * 64 + oo];
    u16x8 pk;
#pragma unroll
    for (int j = 0; j < 8; ++j)
      pk[j] = f2bf(lw[ii0 + j][oo] * s[b * 512 + ib * 32 + ii0 + j] * f);
    *(u16x8*)(wwb + ((size_t)(b * 9 + t) * 512 + ob * 64 + oo) * 512 + ib * 32 + ii0) = pk;
  }
}

// ---------- 5a. zero only the 1-px border ring of xpad
__global__ void border_k(u16* __restrict__ xpad) {
  const int idx = blockIdx.x * 256 + threadIdx.x;   // 520*256 = 133120 exact
  const int chunk = idx & 63;
  const int p = (idx >> 6) % 260;
  const int b = idx / (260 * 64);
  int row, col;
  if (p < 66)       { row = 0;       col = p; }
  else if (p < 132) { row = 65;      col = p - 66; }
  else if (p < 196) { row = p - 131; col = 0; }
  else              { row = p - 195; col = 65; }
  u16x8 z = {0, 0, 0, 0, 0, 0, 0, 0};
  *(u16x8*)(xpad + ((size_t)(b * 66 + row) * 66 + col) * 512 + chunk * 8) = z;
}

// ---------- 5b. xpad[b][h+1][wcol+1][i] = bf16(x[b][i][h][wcol])   (NCHW -> padded NHWC)
__global__ void fill_k(const float* __restrict__ x, u16* __restrict__ xpad) {
  const int blk = blockIdx.x;               // 8*64*4 = 2048
  const int ib = blk & 3, hh = (blk >> 2) & 63, b = blk >> 8;
  __shared__ float lx[128][65];
  const int tid = threadIdx.x;
#pragma unroll
  for (int k = 0; k < 2; ++k) {
    const int u = tid + k * 256;
    const int i = u >> 2, w0 = (u & 3) * 16;
    const float* src = x + (size_t)((b * 512 + ib * 128 + i) * 64 + hh) * 64 + w0;
    float tmp[16];
    ((float4*)tmp)[0] = ((const float4*)src)[0];
    ((float4*)tmp)[1] = ((const float4*)src)[1];
    ((float4*)tmp)[2] = ((const float4*)src)[2];
    ((float4*)tmp)[3] = ((const float4*)src)[3];
#pragma unroll
    for (int j = 0; j < 16; ++j) lx[i][w0 + j] = tmp[j];
  }
  __syncthreads();
  const int c = tid >> 2, q = tid & 3;
  const size_t base = ((size_t)(b * 66 + hh + 1) * 66 + (c + 1)) * 512 + ib * 128;
#pragma unroll
  for (int k = 0; k < 4; ++k) {
    const int irow = k * 32 + q * 8;
    u16x8 pk;
#pragma unroll
    for (int j = 0; j < 8; ++j) pk[j] = f2bf(lx[irow + j][c]);
    *(u16x8*)(xpad + base + irow) = pk;
  }
}

// ---------- 6. conv: 32x32x16 MFMA + BK=32 + B-row dedup, r3/r5-proven sync skeleton.
// NO setprio (r9's post-timing race isolated to the setprio x single-buffer combo;
// this kernel is r9 minus setprio as the race-screen A/B).
// block: 256 thr = 4 waves, 64 o x [8 rows x 64 px]; wave = 64o x 2rows x 64px.
// LDS: WS [9 t][64 o][32 i] 36864B + XS [10 r][66 c][32 i] 42240B = 79104B -> 2 blk/CU.
// Serial stage -> vmcnt(0)+barrier -> compute -> barrier; anti-phased blocks overlap.
// Reads use the r2-r7-proven STRIDE-4 chunk pattern (BK=32: chunk = m*4 + i5);
// kh (K-half) = byte-offset ^32 (bit-5 flip commutes with the XOR swizzle).
// B dedup: per tx, rows R0..R3 each read once; tap ty uses (R[ty], R[ty+1]).
// MFMA 32x32x16: A row=l&31(o), k=(l>>5)*8+j (+kh*16); B col=l&31(px), same k;
// D col=lane&31(px), row(o)=(reg&3)+8*(reg>>2)+4*(lane>>5)  [verified r8/r9 on-HW].
__global__ __launch_bounds__(256, 2) void conv_k(const u16* __restrict__ xpad,
                                                 const u16* __restrict__ wwb,
                                                 float* __restrict__ out) {
  __shared__ __align__(1024) char SM[79104];
  const int raw = (int)blockIdx.x;          // 512 blocks
  const int pt = raw >> 6, ot = (raw >> 3) & 7, b = raw & 7;  // XCD b <- batch b
  const int tid = threadIdx.x;
  const int lane = tid & 63, wv = tid >> 6; // wave wv: output rows h0+2wv, h0+2wv+1
  const int h0 = pt * 8;

  const size_t xbase = (size_t)(b * 66 + h0) * (66 * 512);

  // ---- staging source pointers (r3-proven; source-side swizzle, linear LDS dest)
  const u16* aw[9];
  const u16* ax[11];
#pragma unroll
  for (int r = 0; r < 9; ++r) {
    const int cc = tid + r * 256;                 // WS chunks 0..2303
    const int lc = cc ^ ((cc >> 3) & 3);
    const int i8 = lc & 3, o = (lc >> 2) & 63, t = lc >> 8;
    aw[r] = wwb + ((size_t)(b * 9 + t) * 512 + ot * 64 + o) * 512 + i8 * 8;
  }
#pragma unroll
  for (int r = 0; r < 11; ++r) {
    const int c2 = tid + r * 256;                 // XS chunks 0..2639
    const int lc = c2 ^ ((c2 >> 3) & 3);
    const int i8 = lc & 3, rc = lc >> 2;
    ax[r] = xpad + xbase + (size_t)rc * 512 + i8 * 8;
  }
  const bool extra = (tid < 80);                  // 2640 = 10*256 + 80

  // ---- read-side swizzled offsets (stride-4 chunk pattern)
  const int pxl = lane & 31, i5 = lane >> 5;
  const int cbA = pxl * 4 + i5;                   // o = pxl for A
  const int AbO = (cbA ^ ((cbA >> 3) & 3)) * 16;  // + t*4096 + mi*2048, kh: ^32
  int Boff[4][3];
#pragma unroll
  for (int rr = 0; rr < 4; ++rr)
#pragma unroll
    for (int tx = 0; tx < 3; ++tx) {
      const int m = (2 * wv + rr) * 66 + tx + pxl;
      const int ch = m * 4 + i5;
      Boff[rr][tx] = (ch ^ ((ch >> 3) & 3)) * 16; // + n*2048, kh: ^32
    }

  f32x16 acc[2][2][2];                            // [mi][hf][n]
#pragma unroll
  for (int mi = 0; mi < 2; ++mi)
#pragma unroll
    for (int hf = 0; hf < 2; ++hf)
#pragma unroll
      for (int n = 0; n < 2; ++n)
#pragma unroll
        for (int e = 0; e < 16; ++e) acc[mi][hf][n][e] = 0.f;

  // R layout: [n*2 + kh] ; A layout af: [mi*2 + kh]
#define LOADB(R, rr, tx) { \
    const int _o = Boff[rr][tx]; \
    R[0] = *(const bf16x8*)(SM + 36864 + _o); \
    R[1] = *(const bf16x8*)(SM + 36864 + (_o ^ 32)); \
    R[2] = *(const bf16x8*)(SM + 36864 + _o + 2048); \
    R[3] = *(const bf16x8*)(SM + 36864 + ((_o + 2048) ^ 32)); }
#define LOADA(af, t) { \
    const int _a = AbO + (t) * 4096; \
    af[0] = *(const bf16x8*)(SM + _a); \
    af[1] = *(const bf16x8*)(SM + (_a ^ 32)); \
    af[2] = *(const bf16x8*)(SM + _a + 2048); \
    af[3] = *(const bf16x8*)(SM + ((_a + 2048) ^ 32)); }
#define TAP(af, Blo, Bhi) \
    acc[0][0][0] = __builtin_amdgcn_mfma_f32_32x32x16_bf16(af[0], Blo[0], acc[0][0][0], 0, 0, 0); \
    acc[0][0][1] = __builtin_amdgcn_mfma_f32_32x32x16_bf16(af[0], Blo[2], acc[0][0][1], 0, 0, 0); \
    acc[0][1][0] = __builtin_amdgcn_mfma_f32_32x32x16_bf16(af[0], Bhi[0], acc[0][1][0], 0, 0, 0); \
    acc[0][1][1] = __builtin_amdgcn_mfma_f32_32x32x16_bf16(af[0], Bhi[2], acc[0][1][1], 0, 0, 0); \
    acc[1][0][0] = __builtin_amdgcn_mfma_f32_32x32x16_bf16(af[2], Blo[0], acc[1][0][0], 0, 0, 0); \
    acc[1][0][1] = __builtin_amdgcn_mfma_f32_32x32x16_bf16(af[2], Blo[2], acc[1][0][1], 0, 0, 0); \
    acc[1][1][0] = __builtin_amdgcn_mfma_f32_32x32x16_bf16(af[2], Bhi[0], acc[1][1][0], 0, 0, 0); \
    acc[1][1][1] = __builtin_amdgcn_mfma_f32_32x32x16_bf16(af[2], Bhi[2], acc[1][1][1], 0, 0, 0); \
    acc[0][0][0] = __builtin_amdgcn_mfma_f32_32x32x16_bf16(af[1], Blo[1], acc[0][0][0], 0, 0, 0); \
    acc[0][0][1] = __builtin_amdgcn_mfma_f32_32x32x16_bf16(af[1], Blo[3], acc[0][0][1], 0, 0, 0); \
    acc[0][1][0] = __builtin_amdgcn_mfma_f32_32x32x16_bf16(af[1], Bhi[1], acc[0][1][0], 0, 0, 0); \
    acc[0][1][1] = __builtin_amdgcn_mfma_f32_32x32x16_bf16(af[1], Bhi[3], acc[0][1][1], 0, 0, 0); \
    acc[1][0][0] = __builtin_amdgcn_mfma_f32_32x32x16_bf16(af[3], Blo[1], acc[1][0][0], 0, 0, 0); \
    acc[1][0][1] = __builtin_amdgcn_mfma_f32_32x32x16_bf16(af[3], Blo[3], acc[1][0][1], 0, 0, 0); \
    acc[1][1][0] = __builtin_amdgcn_mfma_f32_32x32x16_bf16(af[3], Bhi[1], acc[1][1][0], 0, 0, 0); \
    acc[1][1][1] = __builtin_amdgcn_mfma_f32_32x32x16_bf16(af[3], Bhi[3], acc[1][1][1], 0, 0, 0);

  for (int kb = 0; kb < 16; ++kb) {
    // ---- stage (serial): 9 WS rounds + 10 XS rounds + 80 extra
#pragma unroll
    for (int r = 0; r < 9; ++r)
      gload16(aw[r], SM + (tid + r * 256) * 16);
#pragma unroll
    for (int r = 0; r < 10; ++r)
      gload16(ax[r], SM + 36864 + (tid + r * 256) * 16);
    if (extra) gload16(ax[10], SM + 36864 + (tid + 2560) * 16);
#pragma unroll
    for (int r = 0; r < 9; ++r) aw[r] += 32;
#pragma unroll
    for (int r = 0; r < 11; ++r) ax[r] += 32;
    asm volatile("s_waitcnt vmcnt(0)" ::: "memory");
    __syncthreads();

    // ---- compute: tx-outer, dedup row chain R0..R3
#pragma unroll
    for (int tx = 0; tx < 3; ++tx) {
      bf16x8 R0[4], R1[4], R2[4], R3[4], af0[4], af1[4], af2[4];
      LOADB(R0, 0, tx);
      LOADB(R1, 1, tx);
      LOADA(af0, tx);                 // t = 0*3+tx
      TAP(af0, R0, R1);
      LOADB(R2, 2, tx);
      LOADA(af1, 3 + tx);
      TAP(af1, R1, R2);
      LOADB(R3, 3, tx);
      LOADA(af2, 6 + tx);
      TAP(af2, R2, R3);
    }
    __syncthreads();
  }

  // ---- C write
  const int o4 = i5 * 4;
#pragma unroll
  for (int mi = 0; mi < 2; ++mi)
#pragma unroll
    for (int hf = 0; hf < 2; ++hf) {
      const int h = h0 + 2 * wv + hf;
#pragma unroll
      for (int n = 0; n < 2; ++n) {
        const int wc = n * 32 + pxl;
#pragma unroll
        for (int reg = 0; reg < 16; ++reg) {
          const int o = ot * 64 + mi * 32 + (reg & 3) + 8 * (reg >> 2) + o4;
          out[((size_t)(b * 512 + o) * 64 + h) * 64 + wc] = acc[mi][hf][n][reg];
        }
      }
    }
#undef LOADB
#undef LOADA
#undef TAP
}

extern "C" void kernel_launch(void* const* d_in, const int* in_sizes, int n_in,
                              void* d_out, int out_size, void* d_ws, size_t ws_size,
                              hipStream_t stream) {
  const float* x     = (const float*)d_in[0];   // [8,512,64,64]
  const float* y     = (const float*)d_in[1];   // [8,512]
  const float* w     = (const float*)d_in[2];   // [3,3,512,512]
  const float* w_mod = (const float*)d_in[3];   // [512,512]
  const float* b_mod = (const float*)d_in[4];   // [512]
  float* out = (float*)d_out;

  char* ws = (char*)d_ws;
  float* s    = (float*)(ws);                               // 16 KB
  float* dmd  = (float*)(ws + 16384);                       // 16 KB
  float* wsq  = (float*)(ws + 32768);                       // 1 MB
  u16*   wwb  = (u16*)(ws + 32768 + 1048576);               // 37,748,736 B
  u16*   xpad = (u16*)(ws + 32768 + 1048576 + 37748736);    // 35,684,352 B

  style_k<<<64, 256, 0, stream>>>(y, w_mod, b_mod, s);
  wsq_k<<<1024, 256, 0, stream>>>(w, wsq);
  demod_k<<<64, 256, 0, stream>>>(s, wsq, dmd);
  modw_k<<<1152, 256, 0, stream>>>(w, s, dmd, wwb);
  border_k<<<520, 256, 0, stream>>>(xpad);
  fill_k<<<2048, 256, 0, stream>>>(x, xpad);
  conv_k<<<512, 256, 0, stream>>>(xpad, wwb, out);
}